// Round 3
// baseline (304.326 us; speedup 1.0000x reference)
//
#include <hip/hip_runtime.h>
#include <hip/hip_bf16.h>
#include <math.h>

#define DIM 768
#define NH 12
#define HD 64
#define BATCH 2
#define SEQ 4096
#define MTOT (BATCH * SEQ)   // 8192

// 0.125 (1/sqrt(64)) * log2(e), pre-folded into Q so softmax can use exp2
#define QSCALE 0.1803368801111244f

typedef unsigned short u16;
typedef __bf16 bf16x8 __attribute__((ext_vector_type(8)));
typedef float  f32x4  __attribute__((ext_vector_type(4)));
typedef float  f32x16 __attribute__((ext_vector_type(16)));
typedef unsigned short u16x4 __attribute__((ext_vector_type(4)));
typedef unsigned short u16x8 __attribute__((ext_vector_type(8)));
typedef unsigned u32x4 __attribute__((ext_vector_type(4)));

__device__ inline u16 f2bf(float f) {
    unsigned u = __builtin_bit_cast(unsigned, f);
    u += 0x7fffu + ((u >> 16) & 1u);   // round-to-nearest-even
    return (u16)(u >> 16);
}

// pack two fp32 -> two bf16 (RNE). gfx950 has v_cvt_pk_bf16_f32.
#if defined(__has_builtin) && __has_builtin(__builtin_amdgcn_cvt_pk_bf16_f32)
#define HAVE_PK_BF16 1
__device__ inline unsigned pk2bf(float a, float b) {
    auto v = __builtin_amdgcn_cvt_pk_bf16_f32(a, b);   // D[15:0]=cvt(a), D[31:16]=cvt(b)
    return __builtin_bit_cast(unsigned, v);
}
#else
#define HAVE_PK_BF16 0
__device__ inline unsigned pk2bf(float a, float b) {
    return (unsigned)f2bf(a) | ((unsigned)f2bf(b) << 16);
}
#endif

__device__ inline f32x4 mfma16(bf16x8 a, bf16x8 b, f32x4 c) {
    return __builtin_amdgcn_mfma_f32_16x16x32_bf16(a, b, c, 0, 0, 0);
}
__device__ inline f32x16 mfma32(bf16x8 a, bf16x8 b, f32x16 c) {
    return __builtin_amdgcn_mfma_f32_32x32x16_bf16(a, b, c, 0, 0, 0);
}

// async global->LDS DMA, 16B per lane; LDS dest = wave-uniform base + lane*16
__device__ inline void gl2lds16(const u16* g, u16* l) {
    __builtin_amdgcn_global_load_lds(
        (const __attribute__((address_space(1))) void*)g,
        (__attribute__((address_space(3))) void*)l,
        16, 0, 0);
}

// ---------------------------------------------------------------------------
// fp32 -> bf16 flat copy (8 elems/thread)
// ---------------------------------------------------------------------------
__global__ __launch_bounds__(256)
void cvt_bf16(const float* __restrict__ src, u16* __restrict__ dst, int n8)
{
    int i = blockIdx.x * 256 + threadIdx.x;
    if (i >= n8) return;
    float4 a = ((const float4*)src)[i * 2];
    float4 b = ((const float4*)src)[i * 2 + 1];
    u16x8 o;
    o[0] = f2bf(a.x); o[1] = f2bf(a.y); o[2] = f2bf(a.z); o[3] = f2bf(a.w);
    o[4] = f2bf(b.x); o[5] = f2bf(b.y); o[6] = f2bf(b.z); o[7] = f2bf(b.w);
    ((u16x8*)dst)[i] = o;
}

// ---------------------------------------------------------------------------
// src[R][C] fp32 -> dst[C][R] bf16  (32x32 LDS tiles)
// ---------------------------------------------------------------------------
__global__ __launch_bounds__(256)
void transpose_to_bf16(const float* __restrict__ src, u16* __restrict__ dst,
                       int R, int C)
{
    __shared__ float tile[32][33];
    const int c0 = blockIdx.x * 32, r0 = blockIdx.y * 32;
    const int tx = threadIdx.x & 31, ty = threadIdx.x >> 5;
#pragma unroll
    for (int i = 0; i < 4; ++i) {
        int row = ty * 4 + i;
        tile[row][tx] = src[(size_t)(r0 + row) * C + c0 + tx];
    }
    __syncthreads();
#pragma unroll
    for (int i = 0; i < 4; ++i) {
        int crow = ty * 4 + i;
        dst[(size_t)(c0 + crow) * R + r0 + tx] = f2bf(tile[tx][crow]);
    }
}

// ---------------------------------------------------------------------------
// bf16 MFMA GEMM mainloop with LDS staging (unchanged from R8).
// ---------------------------------------------------------------------------
__device__ inline void gemm_lds_mainloop(const u16* __restrict__ Ag,
                                         const u16* __restrict__ Bg,
                                         int m0, int n0, int w, int lane,
                                         u16 (*As)[64 * 64], u16 (*Bs)[64 * 64],
                                         f32x4 acc[4][4])
{
    const int quad = lane >> 4, lc = lane & 15;
    const int wm = (w & 1) * 64, wn = (w >> 1) * 64;
    const int drow = lane >> 3;   // LDS row within 8-row DMA group
    const int dp   = lane & 7;    // phys chunk within LDS row

#pragma unroll
    for (int mi = 0; mi < 4; ++mi)
#pragma unroll
        for (int nj = 0; nj < 4; ++nj)
            acc[mi][nj] = f32x4{0.f, 0.f, 0.f, 0.f};

    // ---- prime: DMA K-step 0 into buffer 0 ----
#pragma unroll
    for (int i = 0; i < 2; ++i) {
        const int r  = w * 16 + i * 8 + drow;   // LDS row 0..63
        const int g  = dp ^ (r & 7);            // logical chunk
        const int tr = 2 * r + (g >> 2);        // tile row 0..127
        const int kc = g & 3;                   // k-chunk within step
        gl2lds16(Ag + (size_t)(m0 + tr) * 768 + kc * 8, &As[0][(w * 16 + i * 8) * 64]);
        gl2lds16(Bg + (size_t)(n0 + tr) * 768 + kc * 8, &Bs[0][(w * 16 + i * 8) * 64]);
    }
    __syncthreads();

    for (int ks = 0; ks < 24; ++ks) {
        const int cur = ks & 1;

        if (ks < 23) {
            const int k0n = (ks + 1) * 32;
#pragma unroll
            for (int i = 0; i < 2; ++i) {
                const int r  = w * 16 + i * 8 + drow;
                const int g  = dp ^ (r & 7);
                const int tr = 2 * r + (g >> 2);
                const int kc = g & 3;
                gl2lds16(Ag + (size_t)(m0 + tr) * 768 + k0n + kc * 8,
                         &As[1 - cur][(w * 16 + i * 8) * 64]);
                gl2lds16(Bg + (size_t)(n0 + tr) * 768 + k0n + kc * 8,
                         &Bs[1 - cur][(w * 16 + i * 8) * 64]);
            }
        }

        bf16x8 af[4], bfr[4];
#pragma unroll
        for (int mi = 0; mi < 4; ++mi) {
            const int m = wm + mi * 16 + lc;
            const int r = m >> 1;
            const int p = (((m & 1) * 4 + quad)) ^ (r & 7);
            af[mi] = *(const bf16x8*)&As[cur][r * 64 + p * 8];
        }
#pragma unroll
        for (int nj = 0; nj < 4; ++nj) {
            const int n = wn + nj * 16 + lc;
            const int r = n >> 1;
            const int p = (((n & 1) * 4 + quad)) ^ (r & 7);
            bfr[nj] = *(const bf16x8*)&Bs[cur][r * 64 + p * 8];
        }

#pragma unroll
        for (int mi = 0; mi < 4; ++mi)
#pragma unroll
            for (int nj = 0; nj < 4; ++nj)
                acc[mi][nj] = mfma16(af[mi], bfr[nj], acc[mi][nj]);

        __syncthreads();
    }
}

// ---------------------------------------------------------------------------
// GEMM1: [8192,768] @ Wqkvt[2304,768]^T + bqkv -> bf16 Q,K [bh][s][64],
// V transposed [bh][d][s]. Q is pre-scaled by QSCALE for exp2 softmax.
// ---------------------------------------------------------------------------
__global__ __launch_bounds__(256)
void gemm_qkv_mfma(const u16* __restrict__ A, const u16* __restrict__ Bt,
                   const float* __restrict__ bias,
                   u16* __restrict__ Qb, u16* __restrict__ Kb, u16* __restrict__ Vt)
{
    __shared__ u16 As[2][64 * 64];
    __shared__ u16 Bs[2][64 * 64];
    const int m0 = blockIdx.x * 128;
    const int n0 = blockIdx.y * 128;
    const int t = threadIdx.x;
    const int w = t >> 6, lane = t & 63;
    const int quad = lane >> 4, lc = lane & 15;
    const int wm = (w & 1) * 64, wn = (w >> 1) * 64;

    f32x4 acc[4][4];
    gemm_lds_mainloop(A, Bt, m0, n0, w, lane, As, Bs, acc);

    const int b  = m0 >> 12;
    const int s0 = (m0 & 4095) + wm;
    const int nbase = n0 + wn;                 // multiple of 64 -> one (three,h)
    const int three = nbase / 768;
    const int rem   = nbase - three * 768;
    const int h     = rem >> 6;
    const int bh    = b * NH + h;

    if (three < 2) {
        u16* dst = (three == 0) ? Qb : Kb;
        const float qs = (three == 0) ? QSCALE : 1.0f;
#pragma unroll
        for (int nj = 0; nj < 4; ++nj) {
            const float bi = bias[nbase + nj * 16 + lc];
            const int d = nj * 16 + lc;
#pragma unroll
            for (int mi = 0; mi < 4; ++mi) {
                const int s = s0 + mi * 16 + quad * 4;
#pragma unroll
                for (int r = 0; r < 4; ++r)
                    dst[((size_t)bh * SEQ + s + r) * HD + d] = f2bf((acc[mi][nj][r] + bi) * qs);
            }
        }
    } else {
#pragma unroll
        for (int nj = 0; nj < 4; ++nj) {
            const float bi = bias[nbase + nj * 16 + lc];
            const int d = nj * 16 + lc;
            const size_t rowb = ((size_t)bh * HD + d) * SEQ;
#pragma unroll
            for (int mi = 0; mi < 4; ++mi) {
                const int s = s0 + mi * 16 + quad * 4;
                u16x4 wv;
#pragma unroll
                for (int r = 0; r < 4; ++r) wv[r] = f2bf(acc[mi][nj][r] + bi);
                *(u16x4*)&Vt[rowb + s] = wv;
            }
        }
    }
}

// ---------------------------------------------------------------------------
// GEMM3: out[8192,768] = Ao_bf16 @ Wot[768,768]^T + bout (fp32 out)
// ---------------------------------------------------------------------------
__global__ __launch_bounds__(256)
void gemm_out_mfma(const u16* __restrict__ A, const u16* __restrict__ Bt,
                   const float* __restrict__ bias, float* __restrict__ C)
{
    __shared__ u16 As[2][64 * 64];
    __shared__ u16 Bs[2][64 * 64];
    const int m0 = blockIdx.x * 128;
    const int n0 = blockIdx.y * 128;
    const int t = threadIdx.x;
    const int w = t >> 6, lane = t & 63;
    const int quad = lane >> 4, lc = lane & 15;
    const int wm = (w & 1) * 64, wn = (w >> 1) * 64;

    f32x4 acc[4][4];
    gemm_lds_mainloop(A, Bt, m0, n0, w, lane, As, Bs, acc);

#pragma unroll
    for (int nj = 0; nj < 4; ++nj) {
        const int col = n0 + wn + nj * 16 + lc;
        const float bi = bias[col];
#pragma unroll
        for (int mi = 0; mi < 4; ++mi) {
            const int row = m0 + wm + mi * 16 + quad * 4;
#pragma unroll
            for (int r = 0; r < 4; ++r)
                C[(size_t)(row + r) * 768 + col] = acc[mi][nj][r] + bi;
        }
    }
}

// ---------------------------------------------------------------------------
// Flash attention, bf16 MFMA, causal, no-max exp2 softmax, LDS-DMA staged,
// 2D wave split (32q x 32k per wave), XCD-local grid (head-major).
// R11: swapped QK^T on 32x32x16 MFMA, softmax fully in-register (cvt_pk +
// permlane32_swap), no P LDS round-trip.
// R13: SKEWED two-tile pipeline (T15). Iteration t computes QK^T(t+1) on the
// matrix pipe (result s_nxt unused until next iter -> full MFMA latency
// hidden) while softmax(t)+PV(t) run on the VALU from s_cur. Parity-named
// s0/s1 (no runtime indexing). Triple-buffered K/V with rotating indices
// (cb=read-V(t), nb=read-K(t+1), db=DMA-target t+2); ONE vmcnt(0)+s_barrier
// per iter at the top, waiting a DMA issued a full iteration earlier.
// setprio(1) around the QK MFMA cluster (T5). Post-loop __syncthreads
// protects the Vscr/Lx epilogue scratch.
// ---------------------------------------------------------------------------
__global__ __launch_bounds__(256, 3)
void flash_attn(const u16* __restrict__ Qg, const u16* __restrict__ Kg,
                const u16* __restrict__ Vtg, u16* __restrict__ Og)
{
    const int bh   = blockIdx.x;        // 0..23  (x-major => XCD = bh%8)
    const int pair = blockIdx.y;        // 0..31
    const int b    = bh / NH, h = bh % NH;
    const int t    = threadIdx.x;
    const int w    = t >> 6;
    const int wq   = w >> 1;            // q-half (0,1)
    const int wk   = w & 1;             // key-half (0,1)
    const int lane = t & 63;
    const int lc32 = lane & 31;
    const int hi   = lane >> 5;
    const int drow = lane >> 3;         // DMA: row within 8-row group
    const int dp   = lane & 7;          // DMA: chunk position in LDS row

    __shared__ u16 Ks[3][64 * 64];      // [buf][key*64 + d], swizzled chunks
    __shared__ u16 Vs[3][64 * 64];      // [buf][d*64 + s-kb], swizzled chunks

    const u16* Qp = Qg  + (size_t)bh * SEQ * HD;
    const u16* Kp = Kg  + (size_t)bh * SEQ * HD;
    const u16* Vp = Vtg + (size_t)bh * HD * SEQ;   // [d][s]
    float* Vscr = (float*)&Vs[0][0];    // 16 KB scratch for O cross-wave sum
    float* Lx   = (float*)&Ks[0][0];    // epilogue-only: Ks dead there

    const int krow = wk * 32 + lc32;    // this wave's K row in LDS
    const int ksw  = krow & 7;

#pragma unroll 1
    for (int half = 0; half < 2; ++half) {
        const int qt    = half ? pair : (63 - pair);   // long tile first
        const int qrow0 = qt * 64 + wq * 32;

        // ---- prologue: DMA(0)->b0, Q loads, DMA(1)->b1 (vmcnt order!) ----
#pragma unroll
        for (int i = 0; i < 2; ++i) {
            const int r0  = w * 16 + i * 8;
            const int row = r0 + drow;
            const int gc  = dp ^ (row & 7);
            gl2lds16(Kp + (size_t)row * HD + gc * 8, &Ks[0][r0 * 64]);
            gl2lds16(Vp + (size_t)row * SEQ + gc * 8, &Vs[0][r0 * 64]);
        }

        // Q B-frags (32x32x16): row=q=lane&31, k=d=ds*16+hi*8+j.
        bf16x8 qa[4];
#pragma unroll
        for (int ds = 0; ds < 4; ++ds)
            qa[ds] = *(const bf16x8*)
                &Qp[(size_t)(qrow0 + lc32) * HD + ds * 16 + hi * 8];

        if (qt >= 1) {
#pragma unroll
            for (int i = 0; i < 2; ++i) {
                const int r0  = w * 16 + i * 8;
                const int row = r0 + drow;
                const int gc  = dp ^ (row & 7);
                gl2lds16(Kp + (size_t)(64 + row) * HD + gc * 8, &Ks[1][r0 * 64]);
                gl2lds16(Vp + (size_t)row * SEQ + 64 + gc * 8, &Vs[1][r0 * 64]);
            }
        }

        f32x16 o2[2];                  // O^ [q(32)][d-tile(32)] x2, C-layout
        o2[0] = f32x16{};
        o2[1] = f32x16{};
        float l_r = 0.f;               // per-lane denom partial, q = lc32

        // retire Q + DMA(0); leave DMA(1)'s 4 in flight
        if (qt >= 1) { asm volatile("s_waitcnt vmcnt(4)" ::: "memory"); }
        else         { asm volatile("s_waitcnt vmcnt(0)" ::: "memory"); }
        __builtin_amdgcn_s_barrier();

        auto maskf = [&](f32x16& s, int kb) {
            const int q = qrow0 + lc32;
#pragma unroll
            for (int r = 0; r < 16; ++r) {
                const int key = kb + wk * 32 + (r & 3) + 8 * (r >> 2) + 4 * hi;
                if (key > q) s[r] = -1e30f;
            }
        };

        // ---- QK^T(0) from buf 0 ----
        f32x16 s0 = {}, s1 = {};
        {
            __builtin_amdgcn_s_setprio(1);
#pragma unroll
            for (int ds = 0; ds < 4; ++ds) {
                bf16x8 kf = *(const bf16x8*)
                    &Ks[0][krow * 64 + (((ds * 2 + hi) ^ ksw) * 8)];
                s0 = mfma32(kf, qa[ds], s0);
            }
            __builtin_amdgcn_s_setprio(0);
        }
        if (qt == 0) maskf(s0, 0);

        int cb = 0, nb = 1, db = 2;

        // step(t): [sync; DMA(t+2); QK^T(t+1)->snxt] ; softmax(scur) ; PV(t)
        auto step = [&](f32x16& scur, f32x16& snxt, int tk) {
            const int kb = tk * 64;
            if (tk + 1 <= qt) {
                asm volatile("s_waitcnt vmcnt(0)" ::: "memory");
                __builtin_amdgcn_s_barrier();
                if (tk + 2 <= qt) {
                    const int kb2 = kb + 128;
#pragma unroll
                    for (int i = 0; i < 2; ++i) {
                        const int r0  = w * 16 + i * 8;
                        const int row = r0 + drow;
                        const int gc  = dp ^ (row & 7);
                        gl2lds16(Kp + (size_t)(kb2 + row) * HD + gc * 8,
                                 &Ks[db][r0 * 64]);
                        gl2lds16(Vp + (size_t)row * SEQ + kb2 + gc * 8,
                                 &Vs[db][r0 * 64]);
                    }
                }
                // QK^T(tk+1): result dead until next iter -> latency hidden
                snxt = f32x16{};
                __builtin_amdgcn_s_setprio(1);
#pragma unroll
                for (int ds = 0; ds < 4; ++ds) {
                    bf16x8 kf = *(const bf16x8*)
                        &Ks[nb][krow * 64 + (((ds * 2 + hi) ^ ksw) * 8)];
                    snxt = mfma32(kf, qa[ds], snxt);
                }
                __builtin_amdgcn_s_setprio(0);
                if (tk + 1 == qt) maskf(snxt, kb + 64);
            }

            // ---- softmax(tk) on scur: p = exp2(s), all in-register ----
            float pv[16];
#pragma unroll
            for (int r = 0; r < 16; ++r)
                pv[r] = __builtin_amdgcn_exp2f(scur[r]);

            l_r += (((pv[0] + pv[1]) + (pv[2] + pv[3]))
                  + ((pv[4] + pv[5]) + (pv[6] + pv[7])))
                 + (((pv[8] + pv[9]) + (pv[10] + pv[11]))
                  + ((pv[12] + pv[13]) + (pv[14] + pv[15])));

            // P -> bf16 PV A-frags: 4x cvt_pk + 2x permlane32_swap / 16-k.
            bf16x8 pa[2];
#pragma unroll
            for (int s = 0; s < 2; ++s) {
                unsigned w0 = pk2bf(pv[8 * s + 0], pv[8 * s + 1]);
                unsigned w1 = pk2bf(pv[8 * s + 2], pv[8 * s + 3]);
                unsigned w2 = pk2bf(pv[8 * s + 4], pv[8 * s + 5]);
                unsigned w3 = pk2bf(pv[8 * s + 6], pv[8 * s + 7]);
                asm("v_permlane32_swap_b32 %0, %1" : "+v"(w0), "+v"(w2));
                asm("v_permlane32_swap_b32 %0, %1" : "+v"(w1), "+v"(w3));
                u32x4 tw;
                tw[0] = w0; tw[1] = w1; tw[2] = w2; tw[3] = w3;
                pa[s] = __builtin_bit_cast(bf16x8, tw);
            }

            // ---- PV(tk): O[32q][2x32d] += P @ V, from Vs[cb] ----
            __builtin_amdgcn_s_setprio(1);
#pragma unroll
            for (int dt = 0; dt < 2; ++dt) {
                const int row = dt * 32 + lc32;       // d row in Vs
                const int sw  = row & 7;
#pragma unroll
                for (int s = 0; s < 2; ++s) {
                    bf16x8 vf = *(const bf16x8*)
                        &Vs[cb][row * 64 + (((wk * 4 + s * 2 + hi) ^ sw) * 8)];
                    o2[dt] = mfma32(pa[s], vf, o2[dt]);
                }
            }
            __builtin_amdgcn_s_setprio(0);
        };

#pragma unroll 1
        for (int tk = 0; tk <= qt; ++tk) {
            if ((tk & 1) == 0) step(s0, s1, tk);
            else               step(s1, s0, tk);
            const int tmp = cb; cb = nb; nb = db; db = tmp;   // rotate bufs
        }

        __syncthreads();   // all waves done reading Ks/Vs before scratch reuse

        // ---- finish l: own half-keys + partner half (lane^32), one q/lane ----
        const float lt = l_r + __shfl_xor(l_r, 32);

        // ---- cross-wave (wk) reduction of O and l via LDS scratch ----
        if (wk == 1) {
#pragma unroll
            for (int dt = 0; dt < 2; ++dt)
#pragma unroll
                for (int r = 0; r < 16; ++r) {
                    const int ql = (r & 3) + 8 * (r >> 2) + 4 * hi;
                    Vscr[wq * 2048 + ql * 64 + dt * 32 + lc32] = o2[dt][r];
                }
            if (lane < 32) Lx[wq * 32 + lc32] = lt;
        }
        __syncthreads();
        if (wk == 0) {
            const float linv_q = 1.0f / (lt + Lx[wq * 32 + lc32]);  // q = lc32
#pragma unroll
            for (int r = 0; r < 16; ++r) {
                const int ql   = (r & 3) + 8 * (r >> 2) + 4 * hi;
                const float li = __shfl(linv_q, ql);   // lane ql holds q=ql
                const int q = qrow0 + ql;
                const size_t base = ((size_t)(b * SEQ + q)) * DIM + h * HD + lc32;
#pragma unroll
                for (int dt = 0; dt < 2; ++dt) {
                    const float ov = o2[dt][r]
                        + Vscr[wq * 2048 + ql * 64 + dt * 32 + lc32];
                    Og[base + dt * 32] = f2bf(ov * li);
                }
            }
        }
        __syncthreads();   // protect scratch before next half's prime
    }
}

// ---------------------------------------------------------------------------
extern "C" void kernel_launch(void* const* d_in, const int* in_sizes, int n_in,
                              void* d_out, int out_size, void* d_ws, size_t ws_size,
                              hipStream_t stream)
{
    const float* x    = (const float*)d_in[0];   // [2,4096,768]
    const float* Wqkv = (const float*)d_in[1];   // [768,2304]
    const float* bqkv = (const float*)d_in[2];   // [2304]
    const float* Wout = (const float*)d_in[3];   // [768,768]
    const float* bout = (const float*)d_in[4];   // [768]
    float* out = (float*)d_out;                  // [2,4096,768]

    const size_t NX  = (size_t)MTOT * DIM;       // 6,291,456
    const size_t NWQ = (size_t)DIM * 3 * DIM;    // 1,769,472
    const size_t NWO = (size_t)DIM * DIM;        //   589,824
    u16* p   = (u16*)d_ws;
    u16* Xb  = p;              p += NX;
    u16* Wqt = p;              p += NWQ;   // [2304][768]
    u16* Wot = p;              p += NWO;   // [768][768]
    u16* Qb  = p;              p += NX;    // [24][4096][64]
    u16* Kb  = p;              p += NX;
    u16* Vt  = p;              p += NX;    // [24][64][4096]
    u16* Ao  = p;                          // bf16 [8192][768]

    cvt_bf16<<<(int)(NX / 8 + 255) / 256, 256, 0, stream>>>(x, Xb, (int)(NX / 8));
    transpose_to_bf16<<<dim3(2304 / 32, 768 / 32), 256, 0, stream>>>(Wqkv, Wqt, 768, 2304);
    transpose_to_bf16<<<dim3(768 / 32, 768 / 32), 256, 0, stream>>>(Wout, Wot, 768, 768);

    gemm_qkv_mfma<<<dim3(MTOT / 128, 2304 / 128), 256, 0, stream>>>(Xb, Wqt, bqkv, Qb, Kb, Vt);
    flash_attn<<<dim3(24, 32), 256, 0, stream>>>(Qb, Kb, Vt, Ao);
    gemm_out_mfma<<<dim3(MTOT / 128, 768 / 128), 256, 0, stream>>>(Ao, Wot, bout, out);
}

// Round 4
// 248.108 us; speedup vs baseline: 1.2266x; 1.2266x over previous
//
#include <hip/hip_runtime.h>
#include <hip/hip_bf16.h>
#include <math.h>

#define DIM 768
#define NH 12
#define HD 64
#define BATCH 2
#define SEQ 4096
#define MTOT (BATCH * SEQ)   // 8192

// 0.125 (1/sqrt(64)) * log2(e), pre-folded into Q so softmax can use exp2
#define QSCALE 0.1803368801111244f

typedef unsigned short u16;
typedef __bf16 bf16x8 __attribute__((ext_vector_type(8)));
typedef float  f32x4  __attribute__((ext_vector_type(4)));
typedef float  f32x16 __attribute__((ext_vector_type(16)));
typedef unsigned short u16x4 __attribute__((ext_vector_type(4)));
typedef unsigned short u16x8 __attribute__((ext_vector_type(8)));
typedef unsigned u32x4 __attribute__((ext_vector_type(4)));

__device__ inline u16 f2bf(float f) {
    unsigned u = __builtin_bit_cast(unsigned, f);
    u += 0x7fffu + ((u >> 16) & 1u);   // round-to-nearest-even
    return (u16)(u >> 16);
}

// pack two fp32 -> two bf16 (RNE). gfx950 has v_cvt_pk_bf16_f32.
#if defined(__has_builtin) && __has_builtin(__builtin_amdgcn_cvt_pk_bf16_f32)
#define HAVE_PK_BF16 1
__device__ inline unsigned pk2bf(float a, float b) {
    auto v = __builtin_amdgcn_cvt_pk_bf16_f32(a, b);   // D[15:0]=cvt(a), D[31:16]=cvt(b)
    return __builtin_bit_cast(unsigned, v);
}
#else
#define HAVE_PK_BF16 0
__device__ inline unsigned pk2bf(float a, float b) {
    return (unsigned)f2bf(a) | ((unsigned)f2bf(b) << 16);
}
#endif

__device__ inline f32x4 mfma16(bf16x8 a, bf16x8 b, f32x4 c) {
    return __builtin_amdgcn_mfma_f32_16x16x32_bf16(a, b, c, 0, 0, 0);
}
__device__ inline f32x16 mfma32(bf16x8 a, bf16x8 b, f32x16 c) {
    return __builtin_amdgcn_mfma_f32_32x32x16_bf16(a, b, c, 0, 0, 0);
}

// async global->LDS DMA, 16B per lane; LDS dest = wave-uniform base + lane*16
__device__ inline void gl2lds16(const u16* g, u16* l) {
    __builtin_amdgcn_global_load_lds(
        (const __attribute__((address_space(1))) void*)g,
        (__attribute__((address_space(3))) void*)l,
        16, 0, 0);
}

// ---------------------------------------------------------------------------
// fp32 -> bf16 flat copy (8 elems/thread)
// ---------------------------------------------------------------------------
__global__ __launch_bounds__(256)
void cvt_bf16(const float* __restrict__ src, u16* __restrict__ dst, int n8)
{
    int i = blockIdx.x * 256 + threadIdx.x;
    if (i >= n8) return;
    float4 a = ((const float4*)src)[i * 2];
    float4 b = ((const float4*)src)[i * 2 + 1];
    u16x8 o;
    o[0] = f2bf(a.x); o[1] = f2bf(a.y); o[2] = f2bf(a.z); o[3] = f2bf(a.w);
    o[4] = f2bf(b.x); o[5] = f2bf(b.y); o[6] = f2bf(b.z); o[7] = f2bf(b.w);
    ((u16x8*)dst)[i] = o;
}

// ---------------------------------------------------------------------------
// src[R][C] fp32 -> dst[C][R] bf16  (32x32 LDS tiles)
// ---------------------------------------------------------------------------
__global__ __launch_bounds__(256)
void transpose_to_bf16(const float* __restrict__ src, u16* __restrict__ dst,
                       int R, int C)
{
    __shared__ float tile[32][33];
    const int c0 = blockIdx.x * 32, r0 = blockIdx.y * 32;
    const int tx = threadIdx.x & 31, ty = threadIdx.x >> 5;
#pragma unroll
    for (int i = 0; i < 4; ++i) {
        int row = ty * 4 + i;
        tile[row][tx] = src[(size_t)(r0 + row) * C + c0 + tx];
    }
    __syncthreads();
#pragma unroll
    for (int i = 0; i < 4; ++i) {
        int crow = ty * 4 + i;
        dst[(size_t)(c0 + crow) * R + r0 + tx] = f2bf(tile[tx][crow]);
    }
}

// ---------------------------------------------------------------------------
// bf16 MFMA GEMM mainloop with LDS staging (unchanged from R8).
// ---------------------------------------------------------------------------
__device__ inline void gemm_lds_mainloop(const u16* __restrict__ Ag,
                                         const u16* __restrict__ Bg,
                                         int m0, int n0, int w, int lane,
                                         u16 (*As)[64 * 64], u16 (*Bs)[64 * 64],
                                         f32x4 acc[4][4])
{
    const int quad = lane >> 4, lc = lane & 15;
    const int wm = (w & 1) * 64, wn = (w >> 1) * 64;
    const int drow = lane >> 3;   // LDS row within 8-row DMA group
    const int dp   = lane & 7;    // phys chunk within LDS row

#pragma unroll
    for (int mi = 0; mi < 4; ++mi)
#pragma unroll
        for (int nj = 0; nj < 4; ++nj)
            acc[mi][nj] = f32x4{0.f, 0.f, 0.f, 0.f};

    // ---- prime: DMA K-step 0 into buffer 0 ----
#pragma unroll
    for (int i = 0; i < 2; ++i) {
        const int r  = w * 16 + i * 8 + drow;   // LDS row 0..63
        const int g  = dp ^ (r & 7);            // logical chunk
        const int tr = 2 * r + (g >> 2);        // tile row 0..127
        const int kc = g & 3;                   // k-chunk within step
        gl2lds16(Ag + (size_t)(m0 + tr) * 768 + kc * 8, &As[0][(w * 16 + i * 8) * 64]);
        gl2lds16(Bg + (size_t)(n0 + tr) * 768 + kc * 8, &Bs[0][(w * 16 + i * 8) * 64]);
    }
    __syncthreads();

    for (int ks = 0; ks < 24; ++ks) {
        const int cur = ks & 1;

        if (ks < 23) {
            const int k0n = (ks + 1) * 32;
#pragma unroll
            for (int i = 0; i < 2; ++i) {
                const int r  = w * 16 + i * 8 + drow;
                const int g  = dp ^ (r & 7);
                const int tr = 2 * r + (g >> 2);
                const int kc = g & 3;
                gl2lds16(Ag + (size_t)(m0 + tr) * 768 + k0n + kc * 8,
                         &As[1 - cur][(w * 16 + i * 8) * 64]);
                gl2lds16(Bg + (size_t)(n0 + tr) * 768 + k0n + kc * 8,
                         &Bs[1 - cur][(w * 16 + i * 8) * 64]);
            }
        }

        bf16x8 af[4], bfr[4];
#pragma unroll
        for (int mi = 0; mi < 4; ++mi) {
            const int m = wm + mi * 16 + lc;
            const int r = m >> 1;
            const int p = (((m & 1) * 4 + quad)) ^ (r & 7);
            af[mi] = *(const bf16x8*)&As[cur][r * 64 + p * 8];
        }
#pragma unroll
        for (int nj = 0; nj < 4; ++nj) {
            const int n = wn + nj * 16 + lc;
            const int r = n >> 1;
            const int p = (((n & 1) * 4 + quad)) ^ (r & 7);
            bfr[nj] = *(const bf16x8*)&Bs[cur][r * 64 + p * 8];
        }

#pragma unroll
        for (int mi = 0; mi < 4; ++mi)
#pragma unroll
            for (int nj = 0; nj < 4; ++nj)
                acc[mi][nj] = mfma16(af[mi], bfr[nj], acc[mi][nj]);

        __syncthreads();
    }
}

// ---------------------------------------------------------------------------
// GEMM1: [8192,768] @ Wqkvt[2304,768]^T + bqkv -> bf16 Q,K [bh][s][64],
// V transposed [bh][d][s]. Q is pre-scaled by QSCALE for exp2 softmax.
// ---------------------------------------------------------------------------
__global__ __launch_bounds__(256)
void gemm_qkv_mfma(const u16* __restrict__ A, const u16* __restrict__ Bt,
                   const float* __restrict__ bias,
                   u16* __restrict__ Qb, u16* __restrict__ Kb, u16* __restrict__ Vt)
{
    __shared__ u16 As[2][64 * 64];
    __shared__ u16 Bs[2][64 * 64];
    const int m0 = blockIdx.x * 128;
    const int n0 = blockIdx.y * 128;
    const int t = threadIdx.x;
    const int w = t >> 6, lane = t & 63;
    const int quad = lane >> 4, lc = lane & 15;
    const int wm = (w & 1) * 64, wn = (w >> 1) * 64;

    f32x4 acc[4][4];
    gemm_lds_mainloop(A, Bt, m0, n0, w, lane, As, Bs, acc);

    const int b  = m0 >> 12;
    const int s0 = (m0 & 4095) + wm;
    const int nbase = n0 + wn;                 // multiple of 64 -> one (three,h)
    const int three = nbase / 768;
    const int rem   = nbase - three * 768;
    const int h     = rem >> 6;
    const int bh    = b * NH + h;

    if (three < 2) {
        u16* dst = (three == 0) ? Qb : Kb;
        const float qs = (three == 0) ? QSCALE : 1.0f;
#pragma unroll
        for (int nj = 0; nj < 4; ++nj) {
            const float bi = bias[nbase + nj * 16 + lc];
            const int d = nj * 16 + lc;
#pragma unroll
            for (int mi = 0; mi < 4; ++mi) {
                const int s = s0 + mi * 16 + quad * 4;
#pragma unroll
                for (int r = 0; r < 4; ++r)
                    dst[((size_t)bh * SEQ + s + r) * HD + d] = f2bf((acc[mi][nj][r] + bi) * qs);
            }
        }
    } else {
#pragma unroll
        for (int nj = 0; nj < 4; ++nj) {
            const float bi = bias[nbase + nj * 16 + lc];
            const int d = nj * 16 + lc;
            const size_t rowb = ((size_t)bh * HD + d) * SEQ;
#pragma unroll
            for (int mi = 0; mi < 4; ++mi) {
                const int s = s0 + mi * 16 + quad * 4;
                u16x4 wv;
#pragma unroll
                for (int r = 0; r < 4; ++r) wv[r] = f2bf(acc[mi][nj][r] + bi);
                *(u16x4*)&Vt[rowb + s] = wv;
            }
        }
    }
}

// ---------------------------------------------------------------------------
// GEMM3: out[8192,768] = Ao_bf16 @ Wot[768,768]^T + bout (fp32 out)
// ---------------------------------------------------------------------------
__global__ __launch_bounds__(256)
void gemm_out_mfma(const u16* __restrict__ A, const u16* __restrict__ Bt,
                   const float* __restrict__ bias, float* __restrict__ C)
{
    __shared__ u16 As[2][64 * 64];
    __shared__ u16 Bs[2][64 * 64];
    const int m0 = blockIdx.x * 128;
    const int n0 = blockIdx.y * 128;
    const int t = threadIdx.x;
    const int w = t >> 6, lane = t & 63;
    const int quad = lane >> 4, lc = lane & 15;
    const int wm = (w & 1) * 64, wn = (w >> 1) * 64;

    f32x4 acc[4][4];
    gemm_lds_mainloop(A, Bt, m0, n0, w, lane, As, Bs, acc);

#pragma unroll
    for (int nj = 0; nj < 4; ++nj) {
        const int col = n0 + wn + nj * 16 + lc;
        const float bi = bias[col];
#pragma unroll
        for (int mi = 0; mi < 4; ++mi) {
            const int row = m0 + wm + mi * 16 + quad * 4;
#pragma unroll
            for (int r = 0; r < 4; ++r)
                C[(size_t)(row + r) * 768 + col] = acc[mi][nj][r] + bi;
        }
    }
}

// ---------------------------------------------------------------------------
// Flash attention, bf16 MFMA, causal, no-max exp2 softmax, LDS-DMA staged,
// 2D wave split (32q x 32k per wave).
// R11: swapped QK^T on 32x32x16 MFMA, softmax fully in-register (cvt_pk +
// permlane32_swap), no P LDS round-trip. (Best structure: 96.6 us.)
// R14: occupancy push. R3's skewed pipeline spilled to scratch (WRITE_SIZE
// 12->71 MB @ fixed 84 VGPR) -> reverted to R11's loop body exactly.
// Binding constraint was the GRID: 768 equal blocks = 3 blocks/CU while
// 32KB LDS allows 5/CU (5x32KB = 160KB exactly) and 84 VGPR allows 6.
// Now ONE 64-row q-tile per block: grid 24 x 64 = 1536 blocks, ~5
// resident blocks/CU = 20 waves/CU, hiding the serial QK->exp2->pack->PV
// chain. Imbalance (qt+1 steps/block) handled LPT-style: longest tiles
// dispatched first (qt = 63 - blockIdx.y, x-major keeps bh->XCD spread);
// short tiles fill the tail. T5 setprio(1) around MFMA clusters
// (independent co-resident blocks, m191 regime).
// ---------------------------------------------------------------------------
__global__ __launch_bounds__(256, 5)
void flash_attn(const u16* __restrict__ Qg, const u16* __restrict__ Kg,
                const u16* __restrict__ Vtg, u16* __restrict__ Og)
{
    const int bh   = blockIdx.x;        // 0..23  (x-major => XCD = bh%8)
    const int qt   = 63 - (int)blockIdx.y;   // 63..0: longest tiles first
    const int b    = bh / NH, h = bh % NH;
    const int t    = threadIdx.x;
    const int w    = t >> 6;
    const int wq   = w >> 1;            // q-half (0,1)
    const int wk   = w & 1;             // key-half (0,1)
    const int lane = t & 63;
    const int lc32 = lane & 31;
    const int hi   = lane >> 5;
    const int drow = lane >> 3;         // DMA: row within 8-row group
    const int dp   = lane & 7;          // DMA: chunk position in LDS row

    __shared__ u16 Ks[2][64 * 64];      // [buf][key*64 + d], swizzled chunks
    __shared__ u16 Vs[2][64 * 64];      // [buf][d*64 + s-kb], swizzled chunks

    const u16* Qp = Qg  + (size_t)bh * SEQ * HD;
    const u16* Kp = Kg  + (size_t)bh * SEQ * HD;
    const u16* Vp = Vtg + (size_t)bh * HD * SEQ;   // [d][s]
    float* Vscr = (float*)&Vs[0][0];    // 16 KB scratch for O cross-wave sum
    float* Lx   = (float*)&Ks[0][0];    // epilogue-only: Ks dead there

    const int qrow0 = qt * 64 + wq * 32;

    // Q B-frags (32x32x16): row=q=lane&31, k=d=ds*16+hi*8+j. Direct global.
    bf16x8 qa[4];
#pragma unroll
    for (int ds = 0; ds < 4; ++ds)
        qa[ds] = *(const bf16x8*)
            &Qp[(size_t)(qrow0 + lc32) * HD + ds * 16 + hi * 8];

    f32x16 o2[2];                  // O^ [q(32)][d-tile(32)] x2, C-layout
    o2[0] = f32x16{};
    o2[1] = f32x16{};
    float l_r = 0.f;               // per-lane denom partial, q = lc32

    // ---- prime: DMA tile 0 into buffer 0 ----
#pragma unroll
    for (int i = 0; i < 2; ++i) {
        const int r0  = w * 16 + i * 8;
        const int row = r0 + drow;
        const int gc  = dp ^ (row & 7);
        gl2lds16(Kp + (size_t)row * HD + gc * 8, &Ks[0][r0 * 64]);
        gl2lds16(Vp + (size_t)row * SEQ + gc * 8, &Vs[0][r0 * 64]);
    }
    __syncthreads();

    for (int tk = 0; tk <= qt; ++tk) {
        const int kb  = tk * 64;
        const int cur = tk & 1;

        // ---- issue DMA for tile tk+1 into the other buffer ----
        if (tk < qt) {
            const int kbn = kb + 64;
#pragma unroll
            for (int i = 0; i < 2; ++i) {
                const int r0  = w * 16 + i * 8;
                const int row = r0 + drow;
                const int gc  = dp ^ (row & 7);
                gl2lds16(Kp + (size_t)(kbn + row) * HD + gc * 8,
                         &Ks[1 - cur][r0 * 64]);
                gl2lds16(Vp + (size_t)row * SEQ + kbn + gc * 8,
                         &Vs[1 - cur][r0 * 64]);
            }
        }

        // ---- swapped QK^T: S^T[key(32)][q(32)] = K_tile . Q^T ----
        f32x16 sacc = {};
        {
            const int row = wk * 32 + lc32;       // key row in Ks
            const int sw  = row & 7;
            __builtin_amdgcn_s_setprio(1);
#pragma unroll
            for (int ds = 0; ds < 4; ++ds) {
                bf16x8 kf = *(const bf16x8*)
                    &Ks[cur][row * 64 + (((ds * 2 + hi) ^ sw) * 8)];
                sacc = mfma32(kf, qa[ds], sacc);
            }
            __builtin_amdgcn_s_setprio(0);
        }

        // ---- causal mask (diagonal tile only) ----
        if (tk == qt) {
            const int q = qrow0 + lc32;
#pragma unroll
            for (int r = 0; r < 16; ++r) {
                const int key = kb + wk * 32 + (r & 3) + 8 * (r >> 2) + 4 * hi;
                if (key > q) sacc[r] = -1e30f;
            }
        }

        // ---- no-max softmax: p = exp2(s), all in-register ----
        float pv[16];
#pragma unroll
        for (int r = 0; r < 16; ++r)
            pv[r] = __builtin_amdgcn_exp2f(sacc[r]);

        l_r += (((pv[0] + pv[1]) + (pv[2] + pv[3]))
              + ((pv[4] + pv[5]) + (pv[6] + pv[7])))
             + (((pv[8] + pv[9]) + (pv[10] + pv[11]))
              + ((pv[12] + pv[13]) + (pv[14] + pv[15])));

        // ---- P -> bf16 PV A-frags: 4x cvt_pk + 2x permlane32_swap per
        // 16-k slice. After swap(w0,w2)/swap(w1,w3):
        //   lanes<32:  w0=(k0,k1) w1=(k2,k3) w2=(k4,k5) w3=(k6,k7)
        //   lanes>=32: w0=(k8,k9) w1=(k10,k11) w2=(k12,k13) w3=(k14,k15)
        // = exactly A-layout k=(lane>>5)*8+j for mfma_32x32x16. ----
        bf16x8 pa[2];
#pragma unroll
        for (int s = 0; s < 2; ++s) {
            unsigned w0 = pk2bf(pv[8 * s + 0], pv[8 * s + 1]);
            unsigned w1 = pk2bf(pv[8 * s + 2], pv[8 * s + 3]);
            unsigned w2 = pk2bf(pv[8 * s + 4], pv[8 * s + 5]);
            unsigned w3 = pk2bf(pv[8 * s + 6], pv[8 * s + 7]);
            asm("v_permlane32_swap_b32 %0, %1" : "+v"(w0), "+v"(w2));
            asm("v_permlane32_swap_b32 %0, %1" : "+v"(w1), "+v"(w3));
            u32x4 tw;
            tw[0] = w0; tw[1] = w1; tw[2] = w2; tw[3] = w3;
            pa[s] = __builtin_bit_cast(bf16x8, tw);
        }

        // ---- PV: O[32q][2x32d] += P[32q][32k] @ V[32k][64d] ----
        __builtin_amdgcn_s_setprio(1);
#pragma unroll
        for (int dt = 0; dt < 2; ++dt) {
            const int row = dt * 32 + lc32;       // d row in Vs
            const int sw  = row & 7;
#pragma unroll
            for (int s = 0; s < 2; ++s) {
                bf16x8 vf = *(const bf16x8*)
                    &Vs[cur][row * 64 + (((wk * 4 + s * 2 + hi) ^ sw) * 8)];
                o2[dt] = mfma32(pa[s], vf, o2[dt]);
            }
        }
        __builtin_amdgcn_s_setprio(0);

        __syncthreads();
    }

    // ---- finish l: own half-keys + partner half (lane^32), one q/lane ----
    const float lt = l_r + __shfl_xor(l_r, 32);

    // ---- cross-wave (wk) reduction of O and l via LDS scratch ----
    if (wk == 1) {
#pragma unroll
        for (int dt = 0; dt < 2; ++dt)
#pragma unroll
            for (int r = 0; r < 16; ++r) {
                const int ql = (r & 3) + 8 * (r >> 2) + 4 * hi;
                Vscr[wq * 2048 + ql * 64 + dt * 32 + lc32] = o2[dt][r];
            }
        if (lane < 32) Lx[wq * 32 + lc32] = lt;
    }
    __syncthreads();
    if (wk == 0) {
        const float linv_q = 1.0f / (lt + Lx[wq * 32 + lc32]);  // q = lc32
#pragma unroll
        for (int r = 0; r < 16; ++r) {
            const int ql   = (r & 3) + 8 * (r >> 2) + 4 * hi;
            const float li = __shfl(linv_q, ql);   // lane ql holds q=ql
            const int q = qrow0 + ql;
            const size_t base = ((size_t)(b * SEQ + q)) * DIM + h * HD + lc32;
#pragma unroll
            for (int dt = 0; dt < 2; ++dt) {
                const float ov = o2[dt][r]
                    + Vscr[wq * 2048 + ql * 64 + dt * 32 + lc32];
                Og[base + dt * 32] = f2bf(ov * li);
            }
        }
    }
}

// ---------------------------------------------------------------------------
extern "C" void kernel_launch(void* const* d_in, const int* in_sizes, int n_in,
                              void* d_out, int out_size, void* d_ws, size_t ws_size,
                              hipStream_t stream)
{
    const float* x    = (const float*)d_in[0];   // [2,4096,768]
    const float* Wqkv = (const float*)d_in[1];   // [768,2304]
    const float* bqkv = (const float*)d_in[2];   // [2304]
    const float* Wout = (const float*)d_in[3];   // [768,768]
    const float* bout = (const float*)d_in[4];   // [768]
    float* out = (float*)d_out;                  // [2,4096,768]

    const size_t NX  = (size_t)MTOT * DIM;       // 6,291,456
    const size_t NWQ = (size_t)DIM * 3 * DIM;    // 1,769,472
    const size_t NWO = (size_t)DIM * DIM;        //   589,824
    u16* p   = (u16*)d_ws;
    u16* Xb  = p;              p += NX;
    u16* Wqt = p;              p += NWQ;   // [2304][768]
    u16* Wot = p;              p += NWO;   // [768][768]
    u16* Qb  = p;              p += NX;    // [24][4096][64]
    u16* Kb  = p;              p += NX;
    u16* Vt  = p;              p += NX;    // [24][64][4096]
    u16* Ao  = p;                          // bf16 [8192][768]

    cvt_bf16<<<(int)(NX / 8 + 255) / 256, 256, 0, stream>>>(x, Xb, (int)(NX / 8));
    transpose_to_bf16<<<dim3(2304 / 32, 768 / 32), 256, 0, stream>>>(Wqkv, Wqt, 768, 2304);
    transpose_to_bf16<<<dim3(768 / 32, 768 / 32), 256, 0, stream>>>(Wout, Wot, 768, 768);

    gemm_qkv_mfma<<<dim3(MTOT / 128, 2304 / 128), 256, 0, stream>>>(Xb, Wqt, bqkv, Qb, Kb, Vt);
    flash_attn<<<dim3(24, 64), 256, 0, stream>>>(Qb, Kb, Vt, Ao);
    gemm_out_mfma<<<dim3(MTOT / 128, 768 / 128), 256, 0, stream>>>(Ao, Wot, bout, out);
}

// Round 5
// 239.627 us; speedup vs baseline: 1.2700x; 1.0354x over previous
//
#include <hip/hip_runtime.h>
#include <hip/hip_bf16.h>
#include <math.h>

#define DIM 768
#define NH 12
#define HD 64
#define BATCH 2
#define SEQ 4096
#define MTOT (BATCH * SEQ)   // 8192

// 0.125 (1/sqrt(64)) * log2(e), pre-folded into Q so softmax can use exp2
#define QSCALE 0.1803368801111244f

typedef unsigned short u16;
typedef __bf16 bf16x8 __attribute__((ext_vector_type(8)));
typedef float  f32x4  __attribute__((ext_vector_type(4)));
typedef float  f32x16 __attribute__((ext_vector_type(16)));
typedef unsigned short u16x4 __attribute__((ext_vector_type(4)));
typedef unsigned short u16x8 __attribute__((ext_vector_type(8)));
typedef unsigned u32x4 __attribute__((ext_vector_type(4)));

__device__ inline u16 f2bf(float f) {
    unsigned u = __builtin_bit_cast(unsigned, f);
    u += 0x7fffu + ((u >> 16) & 1u);   // round-to-nearest-even
    return (u16)(u >> 16);
}

// pack two fp32 -> two bf16 (RNE). gfx950 has v_cvt_pk_bf16_f32.
#if defined(__has_builtin) && __has_builtin(__builtin_amdgcn_cvt_pk_bf16_f32)
#define HAVE_PK_BF16 1
__device__ inline unsigned pk2bf(float a, float b) {
    auto v = __builtin_amdgcn_cvt_pk_bf16_f32(a, b);   // D[15:0]=cvt(a), D[31:16]=cvt(b)
    return __builtin_bit_cast(unsigned, v);
}
#else
#define HAVE_PK_BF16 0
__device__ inline unsigned pk2bf(float a, float b) {
    return (unsigned)f2bf(a) | ((unsigned)f2bf(b) << 16);
}
#endif

__device__ inline f32x4 mfma16(bf16x8 a, bf16x8 b, f32x4 c) {
    return __builtin_amdgcn_mfma_f32_16x16x32_bf16(a, b, c, 0, 0, 0);
}
__device__ inline f32x16 mfma32(bf16x8 a, bf16x8 b, f32x16 c) {
    return __builtin_amdgcn_mfma_f32_32x32x16_bf16(a, b, c, 0, 0, 0);
}

// async global->LDS DMA, 16B per lane; LDS dest = wave-uniform base + lane*16
__device__ inline void gl2lds16(const u16* g, u16* l) {
    __builtin_amdgcn_global_load_lds(
        (const __attribute__((address_space(1))) void*)g,
        (__attribute__((address_space(3))) void*)l,
        16, 0, 0);
}

// ---------------------------------------------------------------------------
// fp32 -> bf16 flat copy (8 elems/thread)
// ---------------------------------------------------------------------------
__global__ __launch_bounds__(256)
void cvt_bf16(const float* __restrict__ src, u16* __restrict__ dst, int n8)
{
    int i = blockIdx.x * 256 + threadIdx.x;
    if (i >= n8) return;
    float4 a = ((const float4*)src)[i * 2];
    float4 b = ((const float4*)src)[i * 2 + 1];
    u16x8 o;
    o[0] = f2bf(a.x); o[1] = f2bf(a.y); o[2] = f2bf(a.z); o[3] = f2bf(a.w);
    o[4] = f2bf(b.x); o[5] = f2bf(b.y); o[6] = f2bf(b.z); o[7] = f2bf(b.w);
    ((u16x8*)dst)[i] = o;
}

// ---------------------------------------------------------------------------
// src[R][C] fp32 -> dst[C][R] bf16  (32x32 LDS tiles)
// ---------------------------------------------------------------------------
__global__ __launch_bounds__(256)
void transpose_to_bf16(const float* __restrict__ src, u16* __restrict__ dst,
                       int R, int C)
{
    __shared__ float tile[32][33];
    const int c0 = blockIdx.x * 32, r0 = blockIdx.y * 32;
    const int tx = threadIdx.x & 31, ty = threadIdx.x >> 5;
#pragma unroll
    for (int i = 0; i < 4; ++i) {
        int row = ty * 4 + i;
        tile[row][tx] = src[(size_t)(r0 + row) * C + c0 + tx];
    }
    __syncthreads();
#pragma unroll
    for (int i = 0; i < 4; ++i) {
        int crow = ty * 4 + i;
        dst[(size_t)(c0 + crow) * R + r0 + tx] = f2bf(tile[tx][crow]);
    }
}

// ---------------------------------------------------------------------------
// bf16 MFMA GEMM mainloop with LDS staging (unchanged from R8).
// ---------------------------------------------------------------------------
__device__ inline void gemm_lds_mainloop(const u16* __restrict__ Ag,
                                         const u16* __restrict__ Bg,
                                         int m0, int n0, int w, int lane,
                                         u16 (*As)[64 * 64], u16 (*Bs)[64 * 64],
                                         f32x4 acc[4][4])
{
    const int quad = lane >> 4, lc = lane & 15;
    const int wm = (w & 1) * 64, wn = (w >> 1) * 64;
    const int drow = lane >> 3;   // LDS row within 8-row DMA group
    const int dp   = lane & 7;    // phys chunk within LDS row

#pragma unroll
    for (int mi = 0; mi < 4; ++mi)
#pragma unroll
        for (int nj = 0; nj < 4; ++nj)
            acc[mi][nj] = f32x4{0.f, 0.f, 0.f, 0.f};

    // ---- prime: DMA K-step 0 into buffer 0 ----
#pragma unroll
    for (int i = 0; i < 2; ++i) {
        const int r  = w * 16 + i * 8 + drow;   // LDS row 0..63
        const int g  = dp ^ (r & 7);            // logical chunk
        const int tr = 2 * r + (g >> 2);        // tile row 0..127
        const int kc = g & 3;                   // k-chunk within step
        gl2lds16(Ag + (size_t)(m0 + tr) * 768 + kc * 8, &As[0][(w * 16 + i * 8) * 64]);
        gl2lds16(Bg + (size_t)(n0 + tr) * 768 + kc * 8, &Bs[0][(w * 16 + i * 8) * 64]);
    }
    __syncthreads();

    for (int ks = 0; ks < 24; ++ks) {
        const int cur = ks & 1;

        if (ks < 23) {
            const int k0n = (ks + 1) * 32;
#pragma unroll
            for (int i = 0; i < 2; ++i) {
                const int r  = w * 16 + i * 8 + drow;
                const int g  = dp ^ (r & 7);
                const int tr = 2 * r + (g >> 2);
                const int kc = g & 3;
                gl2lds16(Ag + (size_t)(m0 + tr) * 768 + k0n + kc * 8,
                         &As[1 - cur][(w * 16 + i * 8) * 64]);
                gl2lds16(Bg + (size_t)(n0 + tr) * 768 + k0n + kc * 8,
                         &Bs[1 - cur][(w * 16 + i * 8) * 64]);
            }
        }

        bf16x8 af[4], bfr[4];
#pragma unroll
        for (int mi = 0; mi < 4; ++mi) {
            const int m = wm + mi * 16 + lc;
            const int r = m >> 1;
            const int p = (((m & 1) * 4 + quad)) ^ (r & 7);
            af[mi] = *(const bf16x8*)&As[cur][r * 64 + p * 8];
        }
#pragma unroll
        for (int nj = 0; nj < 4; ++nj) {
            const int n = wn + nj * 16 + lc;
            const int r = n >> 1;
            const int p = (((n & 1) * 4 + quad)) ^ (r & 7);
            bfr[nj] = *(const bf16x8*)&Bs[cur][r * 64 + p * 8];
        }

#pragma unroll
        for (int mi = 0; mi < 4; ++mi)
#pragma unroll
            for (int nj = 0; nj < 4; ++nj)
                acc[mi][nj] = mfma16(af[mi], bfr[nj], acc[mi][nj]);

        __syncthreads();
    }
}

// ---------------------------------------------------------------------------
// GEMM1: [8192,768] @ Wqkvt[2304,768]^T + bqkv -> bf16 Q,K [bh][s][64],
// V transposed [bh][d][s]. Q is pre-scaled by QSCALE for exp2 softmax.
// ---------------------------------------------------------------------------
__global__ __launch_bounds__(256)
void gemm_qkv_mfma(const u16* __restrict__ A, const u16* __restrict__ Bt,
                   const float* __restrict__ bias,
                   u16* __restrict__ Qb, u16* __restrict__ Kb, u16* __restrict__ Vt)
{
    __shared__ u16 As[2][64 * 64];
    __shared__ u16 Bs[2][64 * 64];
    const int m0 = blockIdx.x * 128;
    const int n0 = blockIdx.y * 128;
    const int t = threadIdx.x;
    const int w = t >> 6, lane = t & 63;
    const int quad = lane >> 4, lc = lane & 15;
    const int wm = (w & 1) * 64, wn = (w >> 1) * 64;

    f32x4 acc[4][4];
    gemm_lds_mainloop(A, Bt, m0, n0, w, lane, As, Bs, acc);

    const int b  = m0 >> 12;
    const int s0 = (m0 & 4095) + wm;
    const int nbase = n0 + wn;                 // multiple of 64 -> one (three,h)
    const int three = nbase / 768;
    const int rem   = nbase - three * 768;
    const int h     = rem >> 6;
    const int bh    = b * NH + h;

    if (three < 2) {
        u16* dst = (three == 0) ? Qb : Kb;
        const float qs = (three == 0) ? QSCALE : 1.0f;
#pragma unroll
        for (int nj = 0; nj < 4; ++nj) {
            const float bi = bias[nbase + nj * 16 + lc];
            const int d = nj * 16 + lc;
#pragma unroll
            for (int mi = 0; mi < 4; ++mi) {
                const int s = s0 + mi * 16 + quad * 4;
#pragma unroll
                for (int r = 0; r < 4; ++r)
                    dst[((size_t)bh * SEQ + s + r) * HD + d] = f2bf((acc[mi][nj][r] + bi) * qs);
            }
        }
    } else {
#pragma unroll
        for (int nj = 0; nj < 4; ++nj) {
            const float bi = bias[nbase + nj * 16 + lc];
            const int d = nj * 16 + lc;
            const size_t rowb = ((size_t)bh * HD + d) * SEQ;
#pragma unroll
            for (int mi = 0; mi < 4; ++mi) {
                const int s = s0 + mi * 16 + quad * 4;
                u16x4 wv;
#pragma unroll
                for (int r = 0; r < 4; ++r) wv[r] = f2bf(acc[mi][nj][r] + bi);
                *(u16x4*)&Vt[rowb + s] = wv;
            }
        }
    }
}

// ---------------------------------------------------------------------------
// GEMM3: out[8192,768] = Ao_bf16 @ Wot[768,768]^T + bout (fp32 out)
// ---------------------------------------------------------------------------
__global__ __launch_bounds__(256)
void gemm_out_mfma(const u16* __restrict__ A, const u16* __restrict__ Bt,
                   const float* __restrict__ bias, float* __restrict__ C)
{
    __shared__ u16 As[2][64 * 64];
    __shared__ u16 Bs[2][64 * 64];
    const int m0 = blockIdx.x * 128;
    const int n0 = blockIdx.y * 128;
    const int t = threadIdx.x;
    const int w = t >> 6, lane = t & 63;
    const int quad = lane >> 4, lc = lane & 15;
    const int wm = (w & 1) * 64, wn = (w >> 1) * 64;

    f32x4 acc[4][4];
    gemm_lds_mainloop(A, Bt, m0, n0, w, lane, As, Bs, acc);

#pragma unroll
    for (int nj = 0; nj < 4; ++nj) {
        const int col = n0 + wn + nj * 16 + lc;
        const float bi = bias[col];
#pragma unroll
        for (int mi = 0; mi < 4; ++mi) {
            const int row = m0 + wm + mi * 16 + quad * 4;
#pragma unroll
            for (int r = 0; r < 4; ++r)
                C[(size_t)(row + r) * 768 + col] = acc[mi][nj][r] + bi;
        }
    }
}

// ---------------------------------------------------------------------------
// Flash attention, bf16 MFMA, causal, no-max exp2 softmax, LDS-DMA staged,
// 2D wave split (32q x 32k per wave).
// R11: swapped QK^T on 32x32x16 MFMA, softmax fully in-register (cvt_pk +
// permlane32_swap), no P LDS round-trip. (96.6 us @ 3 blocks/CU.)
// R14: single 64-row q-tile per block -> grid 24x64 = 1536 blocks, LPT
// (longest tile first). Occupancy mechanism confirmed (27->35%) but
// launch_bounds(256,5) capped VGPR at 48 -> o2/qa spilled to scratch
// (WRITE_SIZE 12->30MB), net loss.
// R15: launch_bounds(256,4). VGPR cap 128 fits the ~100-reg live state
// (o2=32, qa=16, sacc=16, pv=16) with NO spill; residency = min(VGPR 4,
// LDS 160/32=5, grid 6) = 4 blocks/CU = 16 waves/CU (+33% TLP vs R11)
// to hide the serial QK->exp2->pack->PV chain. T5 setprio kept.
// ---------------------------------------------------------------------------
__global__ __launch_bounds__(256, 4)
void flash_attn(const u16* __restrict__ Qg, const u16* __restrict__ Kg,
                const u16* __restrict__ Vtg, u16* __restrict__ Og)
{
    const int bh   = blockIdx.x;        // 0..23  (x-major => XCD = bh%8)
    const int qt   = 63 - (int)blockIdx.y;   // 63..0: longest tiles first
    const int b    = bh / NH, h = bh % NH;
    const int t    = threadIdx.x;
    const int w    = t >> 6;
    const int wq   = w >> 1;            // q-half (0,1)
    const int wk   = w & 1;             // key-half (0,1)
    const int lane = t & 63;
    const int lc32 = lane & 31;
    const int hi   = lane >> 5;
    const int drow = lane >> 3;         // DMA: row within 8-row group
    const int dp   = lane & 7;          // DMA: chunk position in LDS row

    __shared__ u16 Ks[2][64 * 64];      // [buf][key*64 + d], swizzled chunks
    __shared__ u16 Vs[2][64 * 64];      // [buf][d*64 + s-kb], swizzled chunks

    const u16* Qp = Qg  + (size_t)bh * SEQ * HD;
    const u16* Kp = Kg  + (size_t)bh * SEQ * HD;
    const u16* Vp = Vtg + (size_t)bh * HD * SEQ;   // [d][s]
    float* Vscr = (float*)&Vs[0][0];    // 16 KB scratch for O cross-wave sum
    float* Lx   = (float*)&Ks[0][0];    // epilogue-only: Ks dead there

    const int qrow0 = qt * 64 + wq * 32;

    // Q B-frags (32x32x16): row=q=lane&31, k=d=ds*16+hi*8+j. Direct global.
    bf16x8 qa[4];
#pragma unroll
    for (int ds = 0; ds < 4; ++ds)
        qa[ds] = *(const bf16x8*)
            &Qp[(size_t)(qrow0 + lc32) * HD + ds * 16 + hi * 8];

    f32x16 o2[2];                  // O^ [q(32)][d-tile(32)] x2, C-layout
    o2[0] = f32x16{};
    o2[1] = f32x16{};
    float l_r = 0.f;               // per-lane denom partial, q = lc32

    // ---- prime: DMA tile 0 into buffer 0 ----
#pragma unroll
    for (int i = 0; i < 2; ++i) {
        const int r0  = w * 16 + i * 8;
        const int row = r0 + drow;
        const int gc  = dp ^ (row & 7);
        gl2lds16(Kp + (size_t)row * HD + gc * 8, &Ks[0][r0 * 64]);
        gl2lds16(Vp + (size_t)row * SEQ + gc * 8, &Vs[0][r0 * 64]);
    }
    __syncthreads();

    for (int tk = 0; tk <= qt; ++tk) {
        const int kb  = tk * 64;
        const int cur = tk & 1;

        // ---- issue DMA for tile tk+1 into the other buffer ----
        if (tk < qt) {
            const int kbn = kb + 64;
#pragma unroll
            for (int i = 0; i < 2; ++i) {
                const int r0  = w * 16 + i * 8;
                const int row = r0 + drow;
                const int gc  = dp ^ (row & 7);
                gl2lds16(Kp + (size_t)(kbn + row) * HD + gc * 8,
                         &Ks[1 - cur][r0 * 64]);
                gl2lds16(Vp + (size_t)row * SEQ + kbn + gc * 8,
                         &Vs[1 - cur][r0 * 64]);
            }
        }

        // ---- swapped QK^T: S^T[key(32)][q(32)] = K_tile . Q^T ----
        f32x16 sacc = {};
        {
            const int row = wk * 32 + lc32;       // key row in Ks
            const int sw  = row & 7;
            __builtin_amdgcn_s_setprio(1);
#pragma unroll
            for (int ds = 0; ds < 4; ++ds) {
                bf16x8 kf = *(const bf16x8*)
                    &Ks[cur][row * 64 + (((ds * 2 + hi) ^ sw) * 8)];
                sacc = mfma32(kf, qa[ds], sacc);
            }
            __builtin_amdgcn_s_setprio(0);
        }

        // ---- causal mask (diagonal tile only) ----
        if (tk == qt) {
            const int q = qrow0 + lc32;
#pragma unroll
            for (int r = 0; r < 16; ++r) {
                const int key = kb + wk * 32 + (r & 3) + 8 * (r >> 2) + 4 * hi;
                if (key > q) sacc[r] = -1e30f;
            }
        }

        // ---- no-max softmax: p = exp2(s), all in-register ----
        float pv[16];
#pragma unroll
        for (int r = 0; r < 16; ++r)
            pv[r] = __builtin_amdgcn_exp2f(sacc[r]);

        l_r += (((pv[0] + pv[1]) + (pv[2] + pv[3]))
              + ((pv[4] + pv[5]) + (pv[6] + pv[7])))
             + (((pv[8] + pv[9]) + (pv[10] + pv[11]))
              + ((pv[12] + pv[13]) + (pv[14] + pv[15])));

        // ---- P -> bf16 PV A-frags: 4x cvt_pk + 2x permlane32_swap per
        // 16-k slice. After swap(w0,w2)/swap(w1,w3):
        //   lanes<32:  w0=(k0,k1) w1=(k2,k3) w2=(k4,k5) w3=(k6,k7)
        //   lanes>=32: w0=(k8,k9) w1=(k10,k11) w2=(k12,k13) w3=(k14,k15)
        // = exactly A-layout k=(lane>>5)*8+j for mfma_32x32x16. ----
        bf16x8 pa[2];
#pragma unroll
        for (int s = 0; s < 2; ++s) {
            unsigned w0 = pk2bf(pv[8 * s + 0], pv[8 * s + 1]);
            unsigned w1 = pk2bf(pv[8 * s + 2], pv[8 * s + 3]);
            unsigned w2 = pk2bf(pv[8 * s + 4], pv[8 * s + 5]);
            unsigned w3 = pk2bf(pv[8 * s + 6], pv[8 * s + 7]);
            asm("v_permlane32_swap_b32 %0, %1" : "+v"(w0), "+v"(w2));
            asm("v_permlane32_swap_b32 %0, %1" : "+v"(w1), "+v"(w3));
            u32x4 tw;
            tw[0] = w0; tw[1] = w1; tw[2] = w2; tw[3] = w3;
            pa[s] = __builtin_bit_cast(bf16x8, tw);
        }

        // ---- PV: O[32q][2x32d] += P[32q][32k] @ V[32k][64d] ----
        __builtin_amdgcn_s_setprio(1);
#pragma unroll
        for (int dt = 0; dt < 2; ++dt) {
            const int row = dt * 32 + lc32;       // d row in Vs
            const int sw  = row & 7;
#pragma unroll
            for (int s = 0; s < 2; ++s) {
                bf16x8 vf = *(const bf16x8*)
                    &Vs[cur][row * 64 + (((wk * 4 + s * 2 + hi) ^ sw) * 8)];
                o2[dt] = mfma32(pa[s], vf, o2[dt]);
            }
        }
        __builtin_amdgcn_s_setprio(0);

        __syncthreads();
    }

    // ---- finish l: own half-keys + partner half (lane^32), one q/lane ----
    const float lt = l_r + __shfl_xor(l_r, 32);

    // ---- cross-wave (wk) reduction of O and l via LDS scratch ----
    if (wk == 1) {
#pragma unroll
        for (int dt = 0; dt < 2; ++dt)
#pragma unroll
            for (int r = 0; r < 16; ++r) {
                const int ql = (r & 3) + 8 * (r >> 2) + 4 * hi;
                Vscr[wq * 2048 + ql * 64 + dt * 32 + lc32] = o2[dt][r];
            }
        if (lane < 32) Lx[wq * 32 + lc32] = lt;
    }
    __syncthreads();
    if (wk == 0) {
        const float linv_q = 1.0f / (lt + Lx[wq * 32 + lc32]);  // q = lc32
#pragma unroll
        for (int r = 0; r < 16; ++r) {
            const int ql   = (r & 3) + 8 * (r >> 2) + 4 * hi;
            const float li = __shfl(linv_q, ql);   // lane ql holds q=ql
            const int q = qrow0 + ql;
            const size_t base = ((size_t)(b * SEQ + q)) * DIM + h * HD + lc32;
#pragma unroll
            for (int dt = 0; dt < 2; ++dt) {
                const float ov = o2[dt][r]
                    + Vscr[wq * 2048 + ql * 64 + dt * 32 + lc32];
                Og[base + dt * 32] = f2bf(ov * li);
            }
        }
    }
}

// ---------------------------------------------------------------------------
extern "C" void kernel_launch(void* const* d_in, const int* in_sizes, int n_in,
                              void* d_out, int out_size, void* d_ws, size_t ws_size,
                              hipStream_t stream)
{
    const float* x    = (const float*)d_in[0];   // [2,4096,768]
    const float* Wqkv = (const float*)d_in[1];   // [768,2304]
    const float* bqkv = (const float*)d_in[2];   // [2304]
    const float* Wout = (const float*)d_in[3];   // [768,768]
    const float* bout = (const float*)d_in[4];   // [768]
    float* out = (float*)d_out;                  // [2,4096,768]

    const size_t NX  = (size_t)MTOT * DIM;       // 6,291,456
    const size_t NWQ = (size_t)DIM * 3 * DIM;    // 1,769,472
    const size_t NWO = (size_t)DIM * DIM;        //   589,824
    u16* p   = (u16*)d_ws;
    u16* Xb  = p;              p += NX;
    u16* Wqt = p;              p += NWQ;   // [2304][768]
    u16* Wot = p;              p += NWO;   // [768][768]
    u16* Qb  = p;              p += NX;    // [24][4096][64]
    u16* Kb  = p;              p += NX;
    u16* Vt  = p;              p += NX;    // [24][64][4096]
    u16* Ao  = p;                          // bf16 [8192][768]

    cvt_bf16<<<(int)(NX / 8 + 255) / 256, 256, 0, stream>>>(x, Xb, (int)(NX / 8));
    transpose_to_bf16<<<dim3(2304 / 32, 768 / 32), 256, 0, stream>>>(Wqkv, Wqt, 768, 2304);
    transpose_to_bf16<<<dim3(768 / 32, 768 / 32), 256, 0, stream>>>(Wout, Wot, 768, 768);

    gemm_qkv_mfma<<<dim3(MTOT / 128, 2304 / 128), 256, 0, stream>>>(Xb, Wqt, bqkv, Qb, Kb, Vt);
    flash_attn<<<dim3(24, 64), 256, 0, stream>>>(Qb, Kb, Vt, Ao);
    gemm_out_mfma<<<dim3(MTOT / 128, 768 / 128), 256, 0, stream>>>(Ao, Wot, bout, out);
}